// Round 1
// baseline (4756.351 us; speedup 1.0000x reference)
//
#include <hip/hip_runtime.h>

#define Bn  64
#define Ln  1024
#define Pn  64
#define Hn  256
#define THn 768
#define ONn 128

typedef __attribute__((ext_vector_type(8))) short short8;
typedef __attribute__((ext_vector_type(4))) float f32x4;

__device__ __forceinline__ unsigned short f2bf(float f) {
    unsigned u = __float_as_uint(f);
    unsigned r = (u + 0x7FFFu + ((u >> 16) & 1u)) >> 16;
    return (unsigned short)r;
}
__device__ __forceinline__ float bf2f(unsigned short s) {
    return __uint_as_float(((unsigned)s) << 16);
}
__device__ __forceinline__ float sigm(float x) { return 1.0f / (1.0f + __expf(-x)); }

// ---------------------------------------------------------------------------
// K1: gi_e[b,t,col] = x[b,t,:] @ W_ih_e[col,:] + b_ih_e[col] (+ b_hh_e[col] for r,z)
// stored bf16. Grid 512, block 256 (4 waves). Wave w covers cols [192w,192w+192).
// ---------------------------------------------------------------------------
__global__ __launch_bounds__(256) void k1_gi(const float* __restrict__ x,
        const float* __restrict__ Wih, const float* __restrict__ bih,
        const float* __restrict__ bhh, unsigned short* __restrict__ gi) {
    const int tid = threadIdx.x;
    const int wv = tid >> 6;
    const int lane = tid & 63;
    const int l15 = lane & 15;
    const int grp = lane >> 4;
    const long row0 = (long)blockIdx.x * 128;

    short8 wf[12][2];
#pragma unroll
    for (int tn = 0; tn < 12; ++tn) {
        const int col = 192 * wv + 16 * tn + l15;
#pragma unroll
        for (int tk = 0; tk < 2; ++tk) {
            const float* p = Wih + (long)col * Pn + 32 * tk + 8 * grp;
            const float4 f0 = *(const float4*)p;
            const float4 f1 = *(const float4*)(p + 4);
            wf[tn][tk][0] = (short)f2bf(f0.x); wf[tn][tk][1] = (short)f2bf(f0.y);
            wf[tn][tk][2] = (short)f2bf(f0.z); wf[tn][tk][3] = (short)f2bf(f0.w);
            wf[tn][tk][4] = (short)f2bf(f1.x); wf[tn][tk][5] = (short)f2bf(f1.y);
            wf[tn][tk][6] = (short)f2bf(f1.z); wf[tn][tk][7] = (short)f2bf(f1.w);
        }
    }
    float biasv[12];
#pragma unroll
    for (int tn = 0; tn < 12; ++tn) {
        const int col = 192 * wv + 16 * tn + l15;
        biasv[tn] = bih[col] + (col < 512 ? bhh[col] : 0.0f); // fold b_hh into r,z gates
    }

    for (int m = 0; m < 8; ++m) {
        const long arow = row0 + 16 * m + l15;
        short8 af[2];
#pragma unroll
        for (int tk = 0; tk < 2; ++tk) {
            const float* p = x + arow * Pn + 32 * tk + 8 * grp;
            const float4 f0 = *(const float4*)p;
            const float4 f1 = *(const float4*)(p + 4);
            af[tk][0] = (short)f2bf(f0.x); af[tk][1] = (short)f2bf(f0.y);
            af[tk][2] = (short)f2bf(f0.z); af[tk][3] = (short)f2bf(f0.w);
            af[tk][4] = (short)f2bf(f1.x); af[tk][5] = (short)f2bf(f1.y);
            af[tk][6] = (short)f2bf(f1.z); af[tk][7] = (short)f2bf(f1.w);
        }
#pragma unroll
        for (int tn = 0; tn < 12; ++tn) {
            f32x4 z4 = {0.f, 0.f, 0.f, 0.f};
            f32x4 acc = __builtin_amdgcn_mfma_f32_16x16x32_bf16(af[0], wf[tn][0], z4, 0, 0, 0);
            acc = __builtin_amdgcn_mfma_f32_16x16x32_bf16(af[1], wf[tn][1], acc, 0, 0, 0);
#pragma unroll
            for (int r = 0; r < 4; ++r) {
                const long row = row0 + 16 * m + 4 * grp + r;
                gi[row * THn + 192 * wv + 16 * tn + l15] = f2bf(acc[r] + biasv[tn]);
            }
        }
    }
}

// ---------------------------------------------------------------------------
// K2/K4: persistent GRU recurrence. One WG (4 waves, 512 VGPR) per batch elem.
// W_hh register-resident as bf16 MFMA B-fragments. Wave w owns hidden slice
// [64w,64w+64) => 12 col-tiles (r,z,n x 4). h state fp32 in regs, bf16 in LDS.
// ---------------------------------------------------------------------------
template<int DEC>
__global__ __launch_bounds__(256, 1) void k_rec(
    const float* __restrict__ Whh, const float* __restrict__ bhh,
    const unsigned short* __restrict__ gi_bf,   // encoder: (B,L,768) bf16
    const float* __restrict__ gi_c,             // decoder: (B,768) f32 (biases folded)
    const float* __restrict__ wproj,            // enc: W_attn (use row0 second half); dec: W_dec_out
    const float* __restrict__ bdec,             // dec: scalar
    const float* __restrict__ s0,               // dec: last_h (B,256) f32
    unsigned short* __restrict__ h_seq,         // enc out: (B,L,256) bf16
    float* __restrict__ h_proj,                 // enc out: (B,L)
    float* __restrict__ last_h,                 // enc out: (B,256) f32
    float* __restrict__ y_out)                  // dec out: (B,L)
{
    const int b = blockIdx.x;
    const int tid = threadIdx.x;
    const int wv = tid >> 6;
    const int lane = tid & 63;
    const int l15 = lane & 15;
    const int grp = lane >> 4;

    __shared__ unsigned short hbuf[2][Hn];
    __shared__ float part[2][4];
    __shared__ float ybuf[Ln];

    // ---- load W_hh fragments into registers (once) ----
    short8 wf[12][8];
#pragma unroll
    for (int tn = 0; tn < 12; ++tn) {
        const int g = tn >> 2, j4 = tn & 3;
        const int col = 256 * g + 64 * wv + 16 * j4 + l15;
#pragma unroll
        for (int tk = 0; tk < 8; ++tk) {
            const float* p = Whh + (long)col * Hn + 32 * tk + 8 * grp;
            const float4 f0 = *(const float4*)p;
            const float4 f1 = *(const float4*)(p + 4);
            wf[tn][tk][0] = (short)f2bf(f0.x); wf[tn][tk][1] = (short)f2bf(f0.y);
            wf[tn][tk][2] = (short)f2bf(f0.z); wf[tn][tk][3] = (short)f2bf(f0.w);
            wf[tn][tk][4] = (short)f2bf(f1.x); wf[tn][tk][5] = (short)f2bf(f1.y);
            wf[tn][tk][6] = (short)f2bf(f1.z); wf[tn][tk][7] = (short)f2bf(f1.w);
        }
    }
    float bhh_n[4];
#pragma unroll
    for (int j = 0; j < 4; ++j) bhh_n[j] = bhh[512 + 64 * wv + 16 * j + l15];

    float dvec[4];
#pragma unroll
    for (int j = 0; j < 4; ++j) {
        const int hidx = 64 * wv + 16 * j + l15;
        dvec[j] = DEC ? wproj[hidx] : wproj[Hn + hidx];
    }
    const float bdec_s = DEC ? bdec[0] : 0.0f;

    float hprev[4];
    unsigned short giA[12], giB[12];
    float gic[12];

    if (!DEC) {
#pragma unroll
        for (int j = 0; j < 4; ++j) hprev[j] = 0.0f;
        ((unsigned*)hbuf)[tid] = 0u;   // zero both buffers (2*256 ushort = 256 dwords)
        const unsigned short* g0 = gi_bf + (long)b * Ln * THn;
#pragma unroll
        for (int g = 0; g < 3; ++g)
#pragma unroll
            for (int j = 0; j < 4; ++j)
                giA[g * 4 + j] = g0[g * 256 + 64 * wv + 16 * j + l15];
    } else {
#pragma unroll
        for (int j = 0; j < 4; ++j) hprev[j] = s0[b * Hn + 64 * wv + 16 * j + l15];
        hbuf[0][tid & 255] = f2bf(s0[b * Hn + (tid & 255)]);
        const float* gd = gi_c + (long)b * THn;
#pragma unroll
        for (int g = 0; g < 3; ++g)
#pragma unroll
            for (int j = 0; j < 4; ++j)
                gic[g * 4 + j] = gd[g * 256 + 64 * wv + 16 * j + l15];
    }
    __syncthreads();

    auto step = [&](int t, unsigned short (&gU)[12], unsigned short (&gP)[12]) {
        const int par = t & 1;
        // 1. prefetch gi[t+1] (encoder only) — stays in flight across the barrier
        if (!DEC) {
            const int t1 = (t + 1 < Ln) ? (t + 1) : t;
            const unsigned short* g1 = gi_bf + ((long)b * Ln + t1) * THn;
#pragma unroll
            for (int g = 0; g < 3; ++g)
#pragma unroll
                for (int j = 0; j < 4; ++j)
                    gP[g * 4 + j] = g1[g * 256 + 64 * wv + 16 * j + l15];
        }
        // 2. gh = h @ Whh^T : 96 MFMAs, A = broadcast h row (all m identical)
        f32x4 acc[12];
#pragma unroll
        for (int tk = 0; tk < 8; ++tk) {
            const short8 af = *(const short8*)&hbuf[par][32 * tk + 8 * grp];
            if (tk == 0) {
                const f32x4 z4 = {0.f, 0.f, 0.f, 0.f};
#pragma unroll
                for (int tn = 0; tn < 12; ++tn)
                    acc[tn] = __builtin_amdgcn_mfma_f32_16x16x32_bf16(af, wf[tn][0], z4, 0, 0, 0);
            } else {
#pragma unroll
                for (int tn = 0; tn < 12; ++tn)
                    acc[tn] = __builtin_amdgcn_mfma_f32_16x16x32_bf16(af, wf[tn][tk], acc[tn], 0, 0, 0);
            }
        }
        // 3. gates (values identical across the four 16-lane groups)
        float hnew[4];
#pragma unroll
        for (int j = 0; j < 4; ++j) {
            const float gir = DEC ? gic[j]     : bf2f(gU[j]);
            const float giz = DEC ? gic[4 + j] : bf2f(gU[4 + j]);
            const float gin = DEC ? gic[8 + j] : bf2f(gU[8 + j]);
            const float r = sigm(acc[j][0] + gir);          // b_hh_r folded upstream
            const float z = sigm(acc[4 + j][0] + giz);      // b_hh_z folded upstream
            const float n = tanhf(gin + r * (acc[8 + j][0] + bhh_n[j]));
            hnew[j] = (1.0f - z) * n + z * hprev[j];
            hprev[j] = hnew[j];
        }
        // 4. publish h (double-buffered) + h_seq store
        const int nxt = par ^ 1;
        if (lane < 16) {
#pragma unroll
            for (int j = 0; j < 4; ++j) {
                const unsigned short hb = f2bf(hnew[j]);
                hbuf[nxt][64 * wv + 16 * j + l15] = hb;
                if (!DEC) h_seq[((long)b * Ln + t) * Hn + 64 * wv + 16 * j + l15] = hb;
            }
        }
        // 5. per-wave dot partial (h_proj for enc, y for dec)
        float dp = hnew[0] * dvec[0] + hnew[1] * dvec[1] + hnew[2] * dvec[2] + hnew[3] * dvec[3];
        dp += __shfl_xor(dp, 1);
        dp += __shfl_xor(dp, 2);
        dp += __shfl_xor(dp, 4);
        dp += __shfl_xor(dp, 8);
        if (lane == 0) part[par][wv] = dp;
        // 6. barrier WITHOUT vmcnt drain (keep gi prefetch in flight)
        asm volatile("s_waitcnt lgkmcnt(0)\n\ts_barrier" ::: "memory");
        // 7. finalize scalar (wave0 lane0)
        if (tid == 0) {
            const float s = part[par][0] + part[par][1] + part[par][2] + part[par][3];
            if (!DEC) h_proj[b * Ln + t] = s;
            else      ybuf[t] = sigm(s + bdec_s);
        }
    };

    for (int t = 0; t < Ln; t += 2) {
        step(t, giA, giB);
        step(t + 1, giB, giA);
    }

    if (!DEC) {
        if (lane < 16) {
#pragma unroll
            for (int j = 0; j < 4; ++j)
                last_h[b * Hn + 64 * wv + 16 * j + l15] = hprev[j];
        }
    } else {
        __syncthreads();
#pragma unroll
        for (int i = 0; i < 4; ++i) y_out[b * Ln + tid + 256 * i] = ybuf[tid + 256 * i];
    }
}

// ---------------------------------------------------------------------------
// K3: alpha = softmax(h_proj[b,:]); c = sum_l alpha*h_seq; gi_d = c@Wihd^T + biases
// ---------------------------------------------------------------------------
__global__ __launch_bounds__(256) void k3_ctx(const float* __restrict__ h_proj,
        const unsigned short* __restrict__ h_seq, const float* __restrict__ Wihd,
        const float* __restrict__ bihd, const float* __restrict__ bhhd,
        float* __restrict__ gi_d) {
    const int b = blockIdx.x;
    const int tid = threadIdx.x;
    const int wv = tid >> 6, lane = tid & 63;
    __shared__ float alpha[Ln];
    __shared__ float red[8];
    __shared__ float cbuf[Hn];

    const float4 hp4 = ((const float4*)(h_proj + (long)b * Ln))[tid];
    float m = fmaxf(fmaxf(hp4.x, hp4.y), fmaxf(hp4.z, hp4.w));
#pragma unroll
    for (int s = 1; s < 64; s <<= 1) m = fmaxf(m, __shfl_xor(m, s));
    if (lane == 0) red[wv] = m;
    __syncthreads();
    m = fmaxf(fmaxf(red[0], red[1]), fmaxf(red[2], red[3]));
    const float e0 = __expf(hp4.x - m), e1 = __expf(hp4.y - m);
    const float e2 = __expf(hp4.z - m), e3 = __expf(hp4.w - m);
    float ss = e0 + e1 + e2 + e3;
#pragma unroll
    for (int s = 1; s < 64; s <<= 1) ss += __shfl_xor(ss, s);
    if (lane == 0) red[4 + wv] = ss;
    __syncthreads();
    const float inv = 1.0f / (red[4] + red[5] + red[6] + red[7]);
    ((float4*)alpha)[tid] = make_float4(e0 * inv, e1 * inv, e2 * inv, e3 * inv);
    __syncthreads();

    float accv = 0.0f;
    const unsigned short* hs = h_seq + (long)b * Ln * Hn + tid;
    for (int l = 0; l < Ln; ++l) accv += alpha[l] * bf2f(hs[(long)l * Hn]);
    cbuf[tid] = accv;
    __syncthreads();

    for (int c = wv; c < THn; c += 4) {
        const float4 wr = ((const float4*)(Wihd + (long)c * Hn))[lane];
        const float4 cc = ((const float4*)cbuf)[lane];
        float p = wr.x * cc.x + wr.y * cc.y + wr.z * cc.z + wr.w * cc.w;
#pragma unroll
        for (int s = 1; s < 64; s <<= 1) p += __shfl_xor(p, s);
        if (lane == 0)
            gi_d[(long)b * THn + c] = p + bihd[c] + (c < 512 ? bhhd[c] : 0.0f);
    }
}

// ---------------------------------------------------------------------------
// K5: out[b,o] = y[b,:] @ W_out[o,:] + b_out[o]
// ---------------------------------------------------------------------------
__global__ __launch_bounds__(256) void k5_out(const float* __restrict__ y,
        const float* __restrict__ Wout, const float* __restrict__ bout,
        float* __restrict__ out) {
    const int b = blockIdx.x;
    const int tid = threadIdx.x, wv = tid >> 6, lane = tid & 63;
    __shared__ float yl[Ln];
    ((float4*)yl)[tid] = ((const float4*)(y + (long)b * Ln))[tid];
    __syncthreads();
    for (int o = wv; o < ONn; o += 4) {
        const float* wr = Wout + (long)o * Ln;
        float p = 0.0f;
#pragma unroll
        for (int i = 0; i < 16; ++i) p += yl[lane + 64 * i] * wr[lane + 64 * i];
#pragma unroll
        for (int s = 1; s < 64; s <<= 1) p += __shfl_xor(p, s);
        if (lane == 0) out[b * ONn + o] = p + bout[o];
    }
}

// ---------------------------------------------------------------------------
extern "C" void kernel_launch(void* const* d_in, const int* in_sizes, int n_in,
                              void* d_out, int out_size, void* d_ws, size_t ws_size,
                              hipStream_t stream) {
    const float* x      = (const float*)d_in[0];
    const float* Wih_e  = (const float*)d_in[1];
    const float* Whh_e  = (const float*)d_in[2];
    const float* bih_e  = (const float*)d_in[3];
    const float* bhh_e  = (const float*)d_in[4];
    const float* Wih_d  = (const float*)d_in[5];
    const float* Whh_d  = (const float*)d_in[6];
    const float* bih_d  = (const float*)d_in[7];
    const float* bhh_d  = (const float*)d_in[8];
    const float* Wdec   = (const float*)d_in[9];
    const float* bdec   = (const float*)d_in[10];
    const float* Wattn  = (const float*)d_in[11];
    const float* Wout   = (const float*)d_in[13];
    const float* bout   = (const float*)d_in[14];
    float* out = (float*)d_out;

    char* ws = (char*)d_ws;
    unsigned short* gi_e  = (unsigned short*)ws;                    // 96 MB
    unsigned short* h_seq = (unsigned short*)(ws + 100663296);      // 32 MB
    float* h_proj = (float*)(ws + 134217728);                       // 1 MB region
    float* last_h = (float*)(ws + 134479872);
    float* gi_d   = (float*)(ws + 134545408);
    float* y      = (float*)(ws + 134742016);

    k1_gi<<<512, 256, 0, stream>>>(x, Wih_e, bih_e, bhh_e, gi_e);
    k_rec<0><<<Bn, 256, 0, stream>>>(Whh_e, bhh_e, gi_e, nullptr, Wattn,
                                     nullptr, nullptr, h_seq, h_proj, last_h, nullptr);
    k3_ctx<<<Bn, 256, 0, stream>>>(h_proj, h_seq, Wih_d, bih_d, bhh_d, gi_d);
    k_rec<1><<<Bn, 256, 0, stream>>>(Whh_d, bhh_d, nullptr, gi_d, Wdec,
                                     bdec, last_h, nullptr, nullptr, nullptr, y);
    k5_out<<<Bn, 256, 0, stream>>>(y, Wout, bout, out);
}

// Round 2
// 3111.686 us; speedup vs baseline: 1.5285x; 1.5285x over previous
//
#include <hip/hip_runtime.h>

#define Bn  64
#define Ln  1024
#define Pn  64
#define Hn  256
#define THn 768
#define ONn 128

typedef __attribute__((ext_vector_type(8))) short short8;
typedef __attribute__((ext_vector_type(4))) float f32x4;

__device__ __forceinline__ unsigned short f2bf(float f) {
    unsigned u = __float_as_uint(f);
    unsigned r = (u + 0x7FFFu + ((u >> 16) & 1u)) >> 16;
    return (unsigned short)r;
}
__device__ __forceinline__ float bf2f(unsigned short s) {
    return __uint_as_float(((unsigned)s) << 16);
}
__device__ __forceinline__ float sigm(float x) { return 1.0f / (1.0f + __expf(-x)); }
// branch-free tanh via v_exp_f32; exact at saturation (exp->inf => 1, exp->0 => -1)
__device__ __forceinline__ float ftanh(float x) { return 1.0f - 2.0f / (__expf(2.0f * x) + 1.0f); }

// ---------------------------------------------------------------------------
// K1: gi_e[b,t,col] = x[b,t,:] @ W_ih_e[col,:] + b_ih_e[col] (+ b_hh_e[col] for r,z)
// stored bf16. Grid 512, block 256 (4 waves). Wave w covers cols [192w,192w+192).
// ---------------------------------------------------------------------------
__global__ __launch_bounds__(256) void k1_gi(const float* __restrict__ x,
        const float* __restrict__ Wih, const float* __restrict__ bih,
        const float* __restrict__ bhh, unsigned short* __restrict__ gi) {
    const int tid = threadIdx.x;
    const int wv = tid >> 6;
    const int lane = tid & 63;
    const int l15 = lane & 15;
    const int grp = lane >> 4;
    const long row0 = (long)blockIdx.x * 128;

    short8 wf[12][2];
#pragma unroll
    for (int tn = 0; tn < 12; ++tn) {
        const int col = 192 * wv + 16 * tn + l15;
#pragma unroll
        for (int tk = 0; tk < 2; ++tk) {
            const float* p = Wih + (long)col * Pn + 32 * tk + 8 * grp;
            const float4 f0 = *(const float4*)p;
            const float4 f1 = *(const float4*)(p + 4);
            wf[tn][tk][0] = (short)f2bf(f0.x); wf[tn][tk][1] = (short)f2bf(f0.y);
            wf[tn][tk][2] = (short)f2bf(f0.z); wf[tn][tk][3] = (short)f2bf(f0.w);
            wf[tn][tk][4] = (short)f2bf(f1.x); wf[tn][tk][5] = (short)f2bf(f1.y);
            wf[tn][tk][6] = (short)f2bf(f1.z); wf[tn][tk][7] = (short)f2bf(f1.w);
        }
    }
    float biasv[12];
#pragma unroll
    for (int tn = 0; tn < 12; ++tn) {
        const int col = 192 * wv + 16 * tn + l15;
        biasv[tn] = bih[col] + (col < 512 ? bhh[col] : 0.0f); // fold b_hh into r,z gates
    }

    for (int m = 0; m < 8; ++m) {
        const long arow = row0 + 16 * m + l15;
        short8 af[2];
#pragma unroll
        for (int tk = 0; tk < 2; ++tk) {
            const float* p = x + arow * Pn + 32 * tk + 8 * grp;
            const float4 f0 = *(const float4*)p;
            const float4 f1 = *(const float4*)(p + 4);
            af[tk][0] = (short)f2bf(f0.x); af[tk][1] = (short)f2bf(f0.y);
            af[tk][2] = (short)f2bf(f0.z); af[tk][3] = (short)f2bf(f0.w);
            af[tk][4] = (short)f2bf(f1.x); af[tk][5] = (short)f2bf(f1.y);
            af[tk][6] = (short)f2bf(f1.z); af[tk][7] = (short)f2bf(f1.w);
        }
#pragma unroll
        for (int tn = 0; tn < 12; ++tn) {
            f32x4 z4 = {0.f, 0.f, 0.f, 0.f};
            f32x4 acc = __builtin_amdgcn_mfma_f32_16x16x32_bf16(af[0], wf[tn][0], z4, 0, 0, 0);
            acc = __builtin_amdgcn_mfma_f32_16x16x32_bf16(af[1], wf[tn][1], acc, 0, 0, 0);
#pragma unroll
            for (int r = 0; r < 4; ++r) {
                const long row = row0 + 16 * m + 4 * grp + r;
                gi[row * THn + 192 * wv + 16 * tn + l15] = f2bf(acc[r] + biasv[tn]);
            }
        }
    }
}

// ---------------------------------------------------------------------------
// K2/K4: persistent GRU recurrence. One WG (8 waves, 512 thr) per batch elem.
// Wave w owns hidden slice [32w,32w+32): 6 col-tiles (r,z,n x 2), 8 k-tiles
// => wf[6][8] = 192 VGPRs (fits the 256 arch-VGPR file -> no AGPR moves).
// h state fp32 in regs, published bf16 via LDS double-buffer; one no-vmcnt-drain
// barrier per step so gi prefetch loads stay in flight.
// ---------------------------------------------------------------------------
template<int DEC>
__global__ __launch_bounds__(512, 2) void k_rec(
    const float* __restrict__ Whh, const float* __restrict__ bhh,
    const unsigned short* __restrict__ gi_bf,   // encoder: (B,L,768) bf16
    const float* __restrict__ gi_c,             // decoder: (B,768) f32 (biases folded)
    const float* __restrict__ wproj,            // enc: W_attn row0 (second half); dec: W_dec_out
    const float* __restrict__ bdec,             // dec: scalar
    const float* __restrict__ s0,               // dec: last_h (B,256) f32
    unsigned short* __restrict__ h_seq,         // enc out: (B,L,256) bf16
    float* __restrict__ h_proj,                 // enc out: (B,L)
    float* __restrict__ last_h,                 // enc out: (B,256) f32
    float* __restrict__ y_out)                  // dec out: (B,L)
{
    const int b = blockIdx.x;
    const int tid = threadIdx.x;
    const int wv = tid >> 6;          // 0..7
    const int lane = tid & 63;
    const int l15 = lane & 15;
    const int grp = lane >> 4;
    const int hb = 32 * wv;           // this wave's hidden-slice base

    __shared__ unsigned short hbuf[2][Hn];
    __shared__ float part[2][8];
    __shared__ float ybuf[Ln];

    // ---- load W_hh fragments into registers (once). tn = g*2+j ----
    short8 wf[6][8];
#pragma unroll
    for (int tn = 0; tn < 6; ++tn) {
        const int g = tn >> 1, j = tn & 1;
        const int col = 256 * g + hb + 16 * j + l15;
#pragma unroll
        for (int tk = 0; tk < 8; ++tk) {
            const float* p = Whh + (long)col * Hn + 32 * tk + 8 * grp;
            const float4 f0 = *(const float4*)p;
            const float4 f1 = *(const float4*)(p + 4);
            wf[tn][tk][0] = (short)f2bf(f0.x); wf[tn][tk][1] = (short)f2bf(f0.y);
            wf[tn][tk][2] = (short)f2bf(f0.z); wf[tn][tk][3] = (short)f2bf(f0.w);
            wf[tn][tk][4] = (short)f2bf(f1.x); wf[tn][tk][5] = (short)f2bf(f1.y);
            wf[tn][tk][6] = (short)f2bf(f1.z); wf[tn][tk][7] = (short)f2bf(f1.w);
        }
    }
    float bhh_n[2], dvec[2];
#pragma unroll
    for (int j = 0; j < 2; ++j) {
        const int hidx = hb + 16 * j + l15;
        bhh_n[j] = bhh[512 + hidx];
        dvec[j] = DEC ? wproj[hidx] : wproj[Hn + hidx];
    }
    const float bdec_s = DEC ? bdec[0] : 0.0f;

    float hprev[2];
    unsigned short giA[6], giB[6];
    float gic[6];

    if (!DEC) {
#pragma unroll
        for (int j = 0; j < 2; ++j) hprev[j] = 0.0f;
        if (tid < 256) { hbuf[0][tid] = 0; hbuf[1][tid] = 0; }
        const unsigned short* g0 = gi_bf + (long)b * Ln * THn;
#pragma unroll
        for (int g = 0; g < 3; ++g)
#pragma unroll
            for (int j = 0; j < 2; ++j)
                giA[g * 2 + j] = g0[256 * g + hb + 16 * j + l15];
    } else {
#pragma unroll
        for (int j = 0; j < 2; ++j) hprev[j] = s0[b * Hn + hb + 16 * j + l15];
        if (tid < 256) hbuf[0][tid] = f2bf(s0[b * Hn + tid]);
        const float* gd = gi_c + (long)b * THn;
#pragma unroll
        for (int g = 0; g < 3; ++g)
#pragma unroll
            for (int j = 0; j < 2; ++j)
                gic[g * 2 + j] = gd[256 * g + hb + 16 * j + l15];
    }
    __syncthreads();

    auto step = [&](int t, unsigned short (&gU)[6], unsigned short (&gP)[6]) {
        const int par = t & 1;
        // 1. prefetch gi[t+1] (encoder only) — stays in flight across the barrier
        if (!DEC) {
            const int t1 = (t + 1 < Ln) ? (t + 1) : t;
            const unsigned short* g1 = gi_bf + ((long)b * Ln + t1) * THn;
#pragma unroll
            for (int g = 0; g < 3; ++g)
#pragma unroll
                for (int j = 0; j < 2; ++j)
                    gP[g * 2 + j] = g1[256 * g + hb + 16 * j + l15];
        }
        // 2. gh = h @ Whh^T : 48 MFMAs/wave, A = broadcast h row
        f32x4 acc[6];
#pragma unroll
        for (int tk = 0; tk < 8; ++tk) {
            const short8 af = *(const short8*)&hbuf[par][32 * tk + 8 * grp];
            if (tk == 0) {
                const f32x4 z4 = {0.f, 0.f, 0.f, 0.f};
#pragma unroll
                for (int tn = 0; tn < 6; ++tn)
                    acc[tn] = __builtin_amdgcn_mfma_f32_16x16x32_bf16(af, wf[tn][0], z4, 0, 0, 0);
            } else {
#pragma unroll
                for (int tn = 0; tn < 6; ++tn)
                    acc[tn] = __builtin_amdgcn_mfma_f32_16x16x32_bf16(af, wf[tn][tk], acc[tn], 0, 0, 0);
            }
        }
        // 3. gates (values identical across the four 16-lane groups)
        float hnew[2];
#pragma unroll
        for (int j = 0; j < 2; ++j) {
            const float gir = DEC ? gic[j]     : bf2f(gU[j]);
            const float giz = DEC ? gic[2 + j] : bf2f(gU[2 + j]);
            const float gin = DEC ? gic[4 + j] : bf2f(gU[4 + j]);
            const float r = sigm(acc[j][0] + gir);          // b_hh_r folded upstream
            const float z = sigm(acc[2 + j][0] + giz);      // b_hh_z folded upstream
            const float n = ftanh(gin + r * (acc[4 + j][0] + bhh_n[j]));
            hnew[j] = (1.0f - z) * n + z * hprev[j];
            hprev[j] = hnew[j];
        }
        // 4. publish h (double-buffered) + h_seq store
        const int nxt = par ^ 1;
        if (lane < 16) {
#pragma unroll
            for (int j = 0; j < 2; ++j) {
                const unsigned short hbv = f2bf(hnew[j]);
                hbuf[nxt][hb + 16 * j + l15] = hbv;
                if (!DEC) h_seq[((long)b * Ln + t) * Hn + hb + 16 * j + l15] = hbv;
            }
        }
        // 5. per-wave dot partial (h_proj for enc, y for dec)
        float dp = hnew[0] * dvec[0] + hnew[1] * dvec[1];
        dp += __shfl_xor(dp, 1);
        dp += __shfl_xor(dp, 2);
        dp += __shfl_xor(dp, 4);
        dp += __shfl_xor(dp, 8);
        if (lane == 0) part[par][wv] = dp;
        // 6. barrier WITHOUT vmcnt drain (keep gi prefetch in flight)
        asm volatile("s_waitcnt lgkmcnt(0)\n\ts_barrier" ::: "memory");
        // 7. finalize scalar (wave0 lane0)
        if (tid == 0) {
            float s = part[par][0] + part[par][1] + part[par][2] + part[par][3]
                    + part[par][4] + part[par][5] + part[par][6] + part[par][7];
            if (!DEC) h_proj[b * Ln + t] = s;
            else      ybuf[t] = sigm(s + bdec_s);
        }
    };

    for (int t = 0; t < Ln; t += 2) {
        step(t, giA, giB);
        step(t + 1, giB, giA);
    }

    if (!DEC) {
        if (lane < 16) {
#pragma unroll
            for (int j = 0; j < 2; ++j)
                last_h[b * Hn + hb + 16 * j + l15] = hprev[j];
        }
    } else {
        __syncthreads();
#pragma unroll
        for (int i = 0; i < 2; ++i) y_out[b * Ln + tid + 512 * i] = ybuf[tid + 512 * i];
    }
}

// ---------------------------------------------------------------------------
// K3: alpha = softmax(h_proj[b,:]); c = sum_l alpha*h_seq; gi_d = c@Wihd^T + biases
// ---------------------------------------------------------------------------
__global__ __launch_bounds__(256) void k3_ctx(const float* __restrict__ h_proj,
        const unsigned short* __restrict__ h_seq, const float* __restrict__ Wihd,
        const float* __restrict__ bihd, const float* __restrict__ bhhd,
        float* __restrict__ gi_d) {
    const int b = blockIdx.x;
    const int tid = threadIdx.x;
    const int wv = tid >> 6, lane = tid & 63;
    __shared__ float alpha[Ln];
    __shared__ float red[8];
    __shared__ float cbuf[Hn];

    const float4 hp4 = ((const float4*)(h_proj + (long)b * Ln))[tid];
    float m = fmaxf(fmaxf(hp4.x, hp4.y), fmaxf(hp4.z, hp4.w));
#pragma unroll
    for (int s = 1; s < 64; s <<= 1) m = fmaxf(m, __shfl_xor(m, s));
    if (lane == 0) red[wv] = m;
    __syncthreads();
    m = fmaxf(fmaxf(red[0], red[1]), fmaxf(red[2], red[3]));
    const float e0 = __expf(hp4.x - m), e1 = __expf(hp4.y - m);
    const float e2 = __expf(hp4.z - m), e3 = __expf(hp4.w - m);
    float ss = e0 + e1 + e2 + e3;
#pragma unroll
    for (int s = 1; s < 64; s <<= 1) ss += __shfl_xor(ss, s);
    if (lane == 0) red[4 + wv] = ss;
    __syncthreads();
    const float inv = 1.0f / (red[4] + red[5] + red[6] + red[7]);
    ((float4*)alpha)[tid] = make_float4(e0 * inv, e1 * inv, e2 * inv, e3 * inv);
    __syncthreads();

    float accv = 0.0f;
    const unsigned short* hs = h_seq + (long)b * Ln * Hn + tid;
    for (int l = 0; l < Ln; ++l) accv += alpha[l] * bf2f(hs[(long)l * Hn]);
    cbuf[tid] = accv;
    __syncthreads();

    for (int c = wv; c < THn; c += 4) {
        const float4 wr = ((const float4*)(Wihd + (long)c * Hn))[lane];
        const float4 cc = ((const float4*)cbuf)[lane];
        float p = wr.x * cc.x + wr.y * cc.y + wr.z * cc.z + wr.w * cc.w;
#pragma unroll
        for (int s = 1; s < 64; s <<= 1) p += __shfl_xor(p, s);
        if (lane == 0)
            gi_d[(long)b * THn + c] = p + bihd[c] + (c < 512 ? bhhd[c] : 0.0f);
    }
}

// ---------------------------------------------------------------------------
// K5: out[b,o] = y[b,:] @ W_out[o,:] + b_out[o]
// ---------------------------------------------------------------------------
__global__ __launch_bounds__(256) void k5_out(const float* __restrict__ y,
        const float* __restrict__ Wout, const float* __restrict__ bout,
        float* __restrict__ out) {
    const int b = blockIdx.x;
    const int tid = threadIdx.x, wv = tid >> 6, lane = tid & 63;
    __shared__ float yl[Ln];
    ((float4*)yl)[tid] = ((const float4*)(y + (long)b * Ln))[tid];
    __syncthreads();
    for (int o = wv; o < ONn; o += 4) {
        const float* wr = Wout + (long)o * Ln;
        float p = 0.0f;
#pragma unroll
        for (int i = 0; i < 16; ++i) p += yl[lane + 64 * i] * wr[lane + 64 * i];
#pragma unroll
        for (int s = 1; s < 64; s <<= 1) p += __shfl_xor(p, s);
        if (lane == 0) out[b * ONn + o] = p + bout[o];
    }
}

// ---------------------------------------------------------------------------
extern "C" void kernel_launch(void* const* d_in, const int* in_sizes, int n_in,
                              void* d_out, int out_size, void* d_ws, size_t ws_size,
                              hipStream_t stream) {
    const float* x      = (const float*)d_in[0];
    const float* Wih_e  = (const float*)d_in[1];
    const float* Whh_e  = (const float*)d_in[2];
    const float* bih_e  = (const float*)d_in[3];
    const float* bhh_e  = (const float*)d_in[4];
    const float* Wih_d  = (const float*)d_in[5];
    const float* Whh_d  = (const float*)d_in[6];
    const float* bih_d  = (const float*)d_in[7];
    const float* bhh_d  = (const float*)d_in[8];
    const float* Wdec   = (const float*)d_in[9];
    const float* bdec   = (const float*)d_in[10];
    const float* Wattn  = (const float*)d_in[11];
    const float* Wout   = (const float*)d_in[13];
    const float* bout   = (const float*)d_in[14];
    float* out = (float*)d_out;

    char* ws = (char*)d_ws;
    unsigned short* gi_e  = (unsigned short*)ws;                    // 96 MB
    unsigned short* h_seq = (unsigned short*)(ws + 100663296);      // 32 MB
    float* h_proj = (float*)(ws + 134217728);
    float* last_h = (float*)(ws + 134479872);
    float* gi_d   = (float*)(ws + 134545408);
    float* y      = (float*)(ws + 134742016);

    k1_gi<<<512, 256, 0, stream>>>(x, Wih_e, bih_e, bhh_e, gi_e);
    k_rec<0><<<Bn, 512, 0, stream>>>(Whh_e, bhh_e, gi_e, nullptr, Wattn,
                                     nullptr, nullptr, h_seq, h_proj, last_h, nullptr);
    k3_ctx<<<Bn, 256, 0, stream>>>(h_proj, h_seq, Wih_d, bih_d, bhh_d, gi_d);
    k_rec<1><<<Bn, 512, 0, stream>>>(Whh_d, bhh_d, nullptr, gi_d, Wdec,
                                     bdec, last_h, nullptr, nullptr, nullptr, y);
    k5_out<<<Bn, 256, 0, stream>>>(y, Wout, bout, out);
}